// Round 6
// baseline (125.847 us; speedup 1.0000x reference)
//
#include <hip/hip_runtime.h>

#define D_DIM 1024
#define B_DIM 128
#define C_DIM 1000
#define M_ALL 1152   // 128 x-rows + 1000 mu-rows + 24 zero-pad rows
#define EPSF 1e-6f

typedef __attribute__((ext_vector_type(8))) short short8;   // 8 bf16 = 16B
typedef __attribute__((ext_vector_type(4))) float f32x4;

static __device__ __forceinline__ unsigned short f2bf(float f) {
    union { float f; unsigned int u; } v; v.f = f;
    unsigned int u = v.u;
    u += 0x7fffu + ((u >> 16) & 1u);   // round-to-nearest-even
    return (unsigned short)(u >> 16);
}
static __device__ __forceinline__ float bf2f(unsigned short s) {
    union { unsigned int u; float f; } v; v.u = ((unsigned int)s) << 16;
    return v.f;
}

// Fragment layout: panel(tile16, kc) = 1KB; element (row,k): kc=k>>5,
// l=((k&31)>>3)*16+(row&15), j=k&7; offset_shorts = (tile*32+kc)*512 + l*8 + j.

// ---------------------------------------------------------------------------
// D1: uv = [x;mu;pad] @ tril(L) directly from fp32. 64x64 tile per block,
// grid (nt=16, mt=18), triangular K-skip. LDS-staged with inline fp32->bf16
// convert; B staged transposed (Bs[n][k] = L[k][n0+n], tril-masked).
// nt==0 blocks also emit eps*||a||^2 and beta.a (plain stores, no atomics).
// Epilogue: per-wave LDS reshuffle -> uv fragment panels (R5-proven).
// ---------------------------------------------------------------------------
__global__ __launch_bounds__(256)
void gemm_uv(const float* __restrict__ x, const float* __restrict__ mu,
             const float* __restrict__ beta, const float* __restrict__ L,
             unsigned short* __restrict__ uv_frag,
             float* __restrict__ eps_nrm, float* __restrict__ bdot) {
    __shared__ __align__(16) unsigned short As[64][72];     // 9216 B
    __shared__ __align__(16) unsigned short Bs[64][72];     // 9216 B
    __shared__ __align__(16) unsigned short wls_all[4096];  // 8192 B (2KB/wave)
    const int tid = threadIdx.x;
    const int nt = blockIdx.x, mt = blockIdx.y;
    const int m0 = mt * 64, n0 = nt * 64;
    const int wv = tid >> 6, lane = tid & 63;
    const int lrow = lane & 15, q = lane >> 4;
    const int wm = (wv & 1) * 32, wn = (wv >> 1) * 32;

    // stage maps
    const int am = tid >> 2, aks = (tid & 3) * 16;   // A: row am, k in [aks, aks+16)
    const int bn4 = (tid & 15) * 4, bkl = tid >> 4;  // B: cols bn4..bn4+3, k rows bkl + p*16
    const int m_abs = m0 + am;
    const float* arow = (m_abs < B_DIM) ? (x + m_abs * D_DIM)
                      : (m_abs < B_DIM + C_DIM) ? (mu + (m_abs - B_DIM) * D_DIM)
                      : (const float*)0;

    float sa = 0.f, sb = 0.f;
    f32x4 acc[2][2] = {};

    for (int k0 = n0; k0 < D_DIM; k0 += 64) {   // tri-skip: k < n0 contributes 0
        // ---- stage A (64 rows x 64 k), coalesced float4, convert to bf16 ----
#pragma unroll
        for (int i = 0; i < 4; ++i) {
            int k = aks + i * 4;
            float4 v = arow ? *(const float4*)(arow + k0 + k)
                            : make_float4(0.f, 0.f, 0.f, 0.f);
            ushort4 o;
            o.x = f2bf(v.x); o.y = f2bf(v.y); o.z = f2bf(v.z); o.w = f2bf(v.w);
            *(ushort4*)&As[am][k] = o;
            if (nt == 0) {   // full-K blocks: row reductions for free
                sa += v.x * v.x + v.y * v.y + v.z * v.z + v.w * v.w;
                float4 bb = *(const float4*)(beta + k0 + k);
                sb += bb.x * v.x + bb.y * v.y + bb.z * v.z + bb.w * v.w;
            }
        }
        // ---- stage B transposed (Bs[n][k] = tril(L)[k0+k][n0+n]) ----
#pragma unroll
        for (int p = 0; p < 4; ++p) {
            int kl = bkl + p * 16;
            int k_abs = k0 + kl, nb = n0 + bn4;
            float4 v = *(const float4*)(L + (size_t)k_abs * D_DIM + nb);
            Bs[bn4 + 0][kl] = (k_abs >= nb + 0) ? f2bf(v.x) : (unsigned short)0;
            Bs[bn4 + 1][kl] = (k_abs >= nb + 1) ? f2bf(v.y) : (unsigned short)0;
            Bs[bn4 + 2][kl] = (k_abs >= nb + 2) ? f2bf(v.z) : (unsigned short)0;
            Bs[bn4 + 3][kl] = (k_abs >= nb + 3) ? f2bf(v.w) : (unsigned short)0;
        }
        __syncthreads();
#pragma unroll
        for (int ks = 0; ks < 64; ks += 32) {
            short8 a0 = *(const short8*)&As[wm + lrow][ks + q * 8];
            short8 a1 = *(const short8*)&As[wm + 16 + lrow][ks + q * 8];
            short8 b0 = *(const short8*)&Bs[wn + lrow][ks + q * 8];
            short8 b1 = *(const short8*)&Bs[wn + 16 + lrow][ks + q * 8];
            acc[0][0] = __builtin_amdgcn_mfma_f32_16x16x32_bf16(a0, b0, acc[0][0], 0, 0, 0);
            acc[0][1] = __builtin_amdgcn_mfma_f32_16x16x32_bf16(a0, b1, acc[0][1], 0, 0, 0);
            acc[1][0] = __builtin_amdgcn_mfma_f32_16x16x32_bf16(a1, b0, acc[1][0], 0, 0, 0);
            acc[1][1] = __builtin_amdgcn_mfma_f32_16x16x32_bf16(a1, b1, acc[1][1], 0, 0, 0);
        }
        __syncthreads();
    }

    if (nt == 0) {   // 4 lanes per row -> group-of-4 reduce, plain store
        sa += __shfl_down(sa, 2); sa += __shfl_down(sa, 1);
        sb += __shfl_down(sb, 2); sb += __shfl_down(sb, 1);
        if ((tid & 3) == 0) { eps_nrm[m_abs] = EPSF * sa; bdot[m_abs] = sb; }
    }

    // ---- reshuffle C-layout (col=lrow+ni*16, row=q*4+r) -> fragment panels ----
    unsigned short* wls = wls_all + wv * 1024;
#pragma unroll
    for (int mi = 0; mi < 2; ++mi)
#pragma unroll
    for (int ni = 0; ni < 2; ++ni) {
        int lp = (ni * 2 + (lrow >> 3)) * 16 + q * 4;
#pragma unroll
        for (int r = 0; r < 4; ++r)
            wls[mi * 512 + (lp + r) * 8 + (lrow & 7)] = f2bf(acc[mi][ni][r]);
    }
    asm volatile("s_waitcnt lgkmcnt(0)" ::: "memory");   // per-wave LDS, no barrier
    const int mt32 = (m0 + wm) >> 5, kc = (n0 + wn) >> 5;
#pragma unroll
    for (int mi = 0; mi < 2; ++mi) {
        short8 vv = *(const short8*)(wls + mi * 512 + lane * 8);
        *(short8*)(uv_frag + ((2 * mt32 + mi) * 32 + kc) * 512 + lane * 8) = vv;
    }
}

// ---------------------------------------------------------------------------
// D2: cross-GEMM + fused epilogue. One wave per 16x16 out tile (8 bt x 63 ct
// = 504 waves = 126 blocks), fragment loads, unroll-8. Computes ||u_b||^2 and
// ||v_c||^2 in-loop from the fragments it already loads (no atomics anywhere).
// ---------------------------------------------------------------------------
__global__ __launch_bounds__(256)
void gemm_cross(const unsigned short* __restrict__ uv_frag,
                const float* __restrict__ eps_nrm, const float* __restrict__ bdot,
                const float* __restrict__ lmbda_p, const float* __restrict__ scale_p,
                float* __restrict__ out) {
    const int wid  = blockIdx.x * 4 + (threadIdx.x >> 6);   // 0..503
    const int lane = threadIdx.x & 63;
    const int lrow = lane & 15, q = lane >> 4;
    const int bt = wid / 63, ct = wid % 63;
    const unsigned short* up = uv_frag + (bt * 32) * 512 + lane * 8;        // u rows
    const unsigned short* vp = uv_frag + ((8 + ct) * 32) * 512 + lane * 8;  // v rows

    f32x4 acc = {};
    float su = 0.f, sv = 0.f;   // this lane's k-quarter of ||u_{bt*16+lrow}||^2, ||v||^2
#pragma unroll 8
    for (int kc = 0; kc < 32; ++kc) {
        short8 a = *(const short8*)(up + kc * 512);
        short8 b = *(const short8*)(vp + kc * 512);
        acc = __builtin_amdgcn_mfma_f32_16x16x32_bf16(a, b, acc, 0, 0, 0);
#pragma unroll
        for (int j = 0; j < 8; ++j) {
            float fa = bf2f((unsigned short)a[j]);
            float fb = bf2f((unsigned short)b[j]);
            su = fmaf(fa, fa, su);
            sv = fmaf(fb, fb, sv);
        }
    }
    // reduce over the 4 k-quarter lanes holding the same row (lane ^ 16, ^ 32)
    su += __shfl_xor(su, 16); su += __shfl_xor(su, 32);   // su = ||u_{bt*16+lrow}||^2
    sv += __shfl_xor(sv, 16); sv += __shfl_xor(sv, 32);   // sv = ||v_{ct*16+lrow}||^2

    // hoist shfl out of the divergent guard (source lanes must be active)
    float nu_r[4];
#pragma unroll
    for (int r = 0; r < 4; ++r) nu_r[r] = __shfl(su, q * 4 + r);

    const float lm = *lmbda_p, sc = *scale_p;
    const int c = ct * 16 + lrow;
    if (c < C_DIM) {
        float base_c = sv + eps_nrm[B_DIM + c];
        float bm = bdot[B_DIM + c];
#pragma unroll
        for (int r = 0; r < 4; ++r) {
            int b = bt * 16 + q * 4 + r;
            float quad = nu_r[r] + base_c - 2.f * acc[r] + eps_nrm[b] + EPSF;
            quad = fmaxf(quad, 0.f);
            float bd = bdot[b] - bm;
            out[b * C_DIM + c] = -sc * (sqrtf(quad) + lm * sqrtf(fmaf(bd, bd, EPSF)));
        }
    }
}

extern "C" void kernel_launch(void* const* d_in, const int* in_sizes, int n_in,
                              void* d_out, int out_size, void* d_ws, size_t ws_size,
                              hipStream_t stream) {
    const float* x     = (const float*)d_in[0];   // [128,1024]
    const float* mu    = (const float*)d_in[1];   // [1000,1024]
    const float* beta  = (const float*)d_in[2];   // [1024]
    const float* L     = (const float*)d_in[3];   // [1024,1024]
    const float* lmbda = (const float*)d_in[4];
    const float* scale = (const float*)d_in[5];
    float* out = (float*)d_out;                   // [128,1000]

    char* ws = (char*)d_ws;
    unsigned short* uv_frag = (unsigned short*)ws;            // 1152*1024*2 = 2359296 B
    float* eps_nrm = (float*)(ws + 2359296);                  // [1152]
    float* bdot    = (float*)(ws + 2359296 + 4608);           // [1152]

    gemm_uv   <<<dim3(16, 18), 256, 0, stream>>>(x, mu, beta, L, uv_frag, eps_nrm, bdot);
    gemm_cross<<<126, 256, 0, stream>>>(uv_frag, eps_nrm, bdot, lmbda, scale, out);
}

// Round 7
// 95.562 us; speedup vs baseline: 1.3169x; 1.3169x over previous
//
#include <hip/hip_runtime.h>

#define D_DIM 1024
#define B_DIM 128
#define C_DIM 1000
#define M_ALL 1152   // 128 x-rows + 1000 mu-rows + 24 zero-pad rows
#define EPSF 1e-6f

typedef __attribute__((ext_vector_type(8))) short short8;   // 8 bf16 = 16B
typedef __attribute__((ext_vector_type(4))) float f32x4;

static __device__ __forceinline__ unsigned short f2bf(float f) {
    union { float f; unsigned int u; } v; v.f = f;
    unsigned int u = v.u;
    u += 0x7fffu + ((u >> 16) & 1u);   // round-to-nearest-even
    return (unsigned short)(u >> 16);
}

// Fragment layout (R4/R5-proven): panel(tile16, kc) = 1KB. Element (row, k):
// kc = k>>5, l = ((k&31)>>3)*16 + (row&15), j = k&7;
// offset_shorts = (tile*32 + kc)*512 + l*8 + j.

// ---------------------------------------------------------------------------
// D1: blocks [0,144): pack 8 A-rows -> fragment bf16 + per-row
// (eps*||a||^2, beta.a). Blocks [144,400): one 64x64 tril(L)^T tile -> frags.
// ---------------------------------------------------------------------------
__global__ __launch_bounds__(256)
void pack_all(const float* __restrict__ x, const float* __restrict__ mu,
              const float* __restrict__ beta, const float* __restrict__ L,
              unsigned short* __restrict__ A_frag, unsigned short* __restrict__ LT_frag,
              float* __restrict__ nrm, float* __restrict__ bdot) {
    __shared__ __align__(16) unsigned short s_tile[64 * 72];
    const int tid = threadIdx.x, bid = blockIdx.x;

    if (bid < 144) {
        const int m = bid * 8 + (tid >> 5);         // 8 rows per block
        const int cg = tid & 31;                    // 32 lanes per row
        const float* arow = (m < B_DIM) ? (x + (size_t)m * D_DIM)
                          : (m < B_DIM + C_DIM) ? (mu + (size_t)(m - B_DIM) * D_DIM)
                          : (const float*)0;
        const int mtile = m >> 4, rl = m & 15;
        const int qk = (cg & 7) >> 1, jj = (cg & 1) * 4;
        float sa = 0.f, sb = 0.f;
#pragma unroll
        for (int pass = 0; pass < 8; ++pass) {
            int k = cg * 4 + pass * 128;
            float4 v = arow ? *(const float4*)(arow + k)
                            : make_float4(0.f, 0.f, 0.f, 0.f);
            ushort4 o;
            o.x = f2bf(v.x); o.y = f2bf(v.y); o.z = f2bf(v.z); o.w = f2bf(v.w);
            int kc = (cg >> 3) + pass * 4;
            *(ushort4*)(A_frag + ((size_t)(mtile * 32 + kc)) * 512 + (qk * 16 + rl) * 8 + jj) = o;
            float4 bb = *(const float4*)(beta + k);
            sa += v.x * v.x + v.y * v.y + v.z * v.z + v.w * v.w;
            sb += bb.x * v.x + bb.y * v.y + bb.z * v.z + bb.w * v.w;
        }
        // reduce across the 32 lanes of this row group (shfl_down stays in-group
        // for the lanes that matter; groups are [0,32) and [32,64) of the wave)
#pragma unroll
        for (int off = 16; off > 0; off >>= 1) {
            sa += __shfl_down(sa, off);
            sb += __shfl_down(sb, off);
        }
        if (cg == 0) { nrm[m] = EPSF * sa; bdot[m] = sb; }   // base; gemm_p adds ||P||^2
    } else {
        const int t = bid - 144;                   // 0..255
        const int k0 = (t >> 4) * 64, n0 = (t & 15) * 64;
        const int tn = tid & 63, tq = tid >> 6;    // tq in 0..3
#pragma unroll
        for (int i = 0; i < 16; ++i) {
            int kk = tq + i * 4;
            int k = k0 + kk, n = n0 + tn;
            float v = (k >= n) ? L[(size_t)k * D_DIM + n] : 0.f;   // coalesced in n
            s_tile[tn * 72 + kk] = f2bf(v);                        // [n][k]
        }
        __syncthreads();
        const int p = tid >> 5, s = tid & 31;      // 8 panels x 32 threads
        const int np = p >> 1, kc2 = p & 1;
        const int ntile = (n0 >> 4) + np, kcg = (k0 >> 5) + kc2;
#pragma unroll
        for (int e = 0; e < 2; ++e) {
            int l = s * 2 + e;
            int lq = l >> 4, nr = l & 15;
            short8 vv = *(const short8*)&s_tile[(np * 16 + nr) * 72 + kc2 * 32 + lq * 8];
            *(short8*)(LT_frag + ((size_t)(ntile * 32 + kcg)) * 512 + l * 8) = vv;
        }
    }
}

// ---------------------------------------------------------------------------
// D2: P = A @ tril(L). One wave per 32x32 tile, 1152 waves = 288 blocks.
// Triangular K-skip; fragment-layout loads; unroll-8 (32 loads in flight).
// Epilogue: ||P_row||^2 atomics + C->fragment reshuffle via per-wave LDS.
// ---------------------------------------------------------------------------
__global__ __launch_bounds__(256)
void gemm_p(const unsigned short* __restrict__ A_frag,
            const unsigned short* __restrict__ LT_frag,
            unsigned short* __restrict__ P_frag, float* __restrict__ nrm) {
    __shared__ __align__(16) unsigned short s_resh[4 * 1024];   // 2KB per wave
    const int wv = threadIdx.x >> 6, lane = threadIdx.x & 63;
    const int wid = blockIdx.x * 4 + wv;           // 0..1151
    const int lrow = lane & 15, q = lane >> 4;
    const int mt = wid >> 5, nt = wid & 31;
    const unsigned short* Ab0 = A_frag  + ((size_t)(2 * mt) * 32) * 512 + lane * 8;
    const unsigned short* Ab1 = Ab0 + 32 * 512;
    const unsigned short* Bb0 = LT_frag + ((size_t)(2 * nt) * 32) * 512 + lane * 8;
    const unsigned short* Bb1 = Bb0 + 32 * 512;

    f32x4 acc[2][2] = {};
#pragma unroll 8
    for (int kc = nt; kc < 32; ++kc) {    // tri-skip: LT zero for k < n
        short8 a0 = *(const short8*)(Ab0 + kc * 512);
        short8 a1 = *(const short8*)(Ab1 + kc * 512);
        short8 b0 = *(const short8*)(Bb0 + kc * 512);
        short8 b1 = *(const short8*)(Bb1 + kc * 512);
        acc[0][0] = __builtin_amdgcn_mfma_f32_16x16x32_bf16(a0, b0, acc[0][0], 0, 0, 0);
        acc[0][1] = __builtin_amdgcn_mfma_f32_16x16x32_bf16(a0, b1, acc[0][1], 0, 0, 0);
        acc[1][0] = __builtin_amdgcn_mfma_f32_16x16x32_bf16(a1, b0, acc[1][0], 0, 0, 0);
        acc[1][1] = __builtin_amdgcn_mfma_f32_16x16x32_bf16(a1, b1, acc[1][1], 0, 0, 0);
    }

    // ||P_row||^2 partials (C layout: col = lrow + ni*16, row = q*4 + r)
#pragma unroll
    for (int mi = 0; mi < 2; ++mi)
#pragma unroll
    for (int r = 0; r < 4; ++r) {
        float s = acc[mi][0][r] * acc[mi][0][r] + acc[mi][1][r] * acc[mi][1][r];
#pragma unroll
        for (int off = 1; off < 16; off <<= 1) s += __shfl_xor(s, off);
        if (lrow == 0) atomicAdd(&nrm[mt * 32 + mi * 16 + q * 4 + r], s);
    }
    // Reshuffle C-layout -> fragment layout through per-wave LDS
    unsigned short* wls = s_resh + wv * 1024;
#pragma unroll
    for (int mi = 0; mi < 2; ++mi)
#pragma unroll
    for (int ni = 0; ni < 2; ++ni) {
        int lp = (ni * 2 + (lrow >> 3)) * 16 + q * 4;
#pragma unroll
        for (int r = 0; r < 4; ++r)
            wls[mi * 512 + (lp + r) * 8 + (lrow & 7)] = f2bf(acc[mi][ni][r]);
    }
    asm volatile("s_waitcnt lgkmcnt(0)" ::: "memory");   // per-wave LDS, no barrier
#pragma unroll
    for (int mi = 0; mi < 2; ++mi) {
        short8 vv = *(const short8*)(wls + mi * 512 + lane * 8);
        *(short8*)(P_frag + ((size_t)((2 * mt + mi) * 32 + nt)) * 512 + lane * 8) = vv;
    }
}

// ---------------------------------------------------------------------------
// D3: cross-GEMM + fused epilogue, split-K x2. 504 tiles x 2 K-halves =
// 1008 wave-jobs = 252 blocks. Each wave: 16 kc iters (unroll 8); K-halves
// combined through LDS inside the block; kh=0 wave runs the epilogue.
// ---------------------------------------------------------------------------
__global__ __launch_bounds__(256)
void gemm_cross(const unsigned short* __restrict__ P_frag,
                const float* __restrict__ nrm, const float* __restrict__ bdot,
                const float* __restrict__ lmbda_p, const float* __restrict__ scale_p,
                float* __restrict__ out) {
    __shared__ f32x4 red[2][64];
    const int wv = threadIdx.x >> 6, lane = threadIdx.x & 63;
    const int tile = blockIdx.x * 2 + (wv >> 1);   // 0..503
    const int kh = wv & 1;
    const int lrow = lane & 15, q = lane >> 4;
    const int bt = tile / 63, ct = tile % 63;
    const unsigned short* up = P_frag + ((size_t)(bt * 32 + kh * 16)) * 512 + lane * 8;
    const unsigned short* vp = P_frag + ((size_t)((8 + ct) * 32 + kh * 16)) * 512 + lane * 8;

    f32x4 acc = {};
#pragma unroll 8
    for (int kc = 0; kc < 16; ++kc) {
        short8 a = *(const short8*)(up + kc * 512);
        short8 b = *(const short8*)(vp + kc * 512);
        acc = __builtin_amdgcn_mfma_f32_16x16x32_bf16(a, b, acc, 0, 0, 0);
    }
    if (kh == 1) red[wv >> 1][lane] = acc;
    __syncthreads();
    if (kh == 1) return;
    f32x4 o = red[wv >> 1][lane];
    acc[0] += o[0]; acc[1] += o[1]; acc[2] += o[2]; acc[3] += o[3];

    const float lm = *lmbda_p, sc = *scale_p;
    const int c = ct * 16 + lrow;
    if (c < C_DIM) {
        float nm = nrm[B_DIM + c], bm = bdot[B_DIM + c];
#pragma unroll
        for (int r = 0; r < 4; ++r) {
            int b = bt * 16 + q * 4 + r;
            float quad = nrm[b] + nm - 2.f * acc[r] + EPSF;
            quad = fmaxf(quad, 0.f);
            float bd = bdot[b] - bm;
            out[b * C_DIM + c] = -sc * (sqrtf(quad) + lm * sqrtf(fmaf(bd, bd, EPSF)));
        }
    }
}

extern "C" void kernel_launch(void* const* d_in, const int* in_sizes, int n_in,
                              void* d_out, int out_size, void* d_ws, size_t ws_size,
                              hipStream_t stream) {
    const float* x     = (const float*)d_in[0];   // [128,1024]
    const float* mu    = (const float*)d_in[1];   // [1000,1024]
    const float* beta  = (const float*)d_in[2];   // [1024]
    const float* L     = (const float*)d_in[3];   // [1024,1024]
    const float* lmbda = (const float*)d_in[4];
    const float* scale = (const float*)d_in[5];
    float* out = (float*)d_out;                   // [128,1000]

    char* ws = (char*)d_ws;
    unsigned short* A_frag  = (unsigned short*)ws;                       // 2359296 B
    unsigned short* LT_frag = (unsigned short*)(ws + 2359296);           // 2097152 B
    unsigned short* P_frag  = (unsigned short*)(ws + 2359296 + 2097152); // 2359296 B
    float* fws  = (float*)(ws + 2359296 + 2097152 + 2359296);
    float* nrm  = fws;             // [1152]
    float* bdot = fws + M_ALL;     // [1152]

    dim3 blk(256);
    pack_all  <<<400, blk, 0, stream>>>(x, mu, beta, L, A_frag, LT_frag, nrm, bdot);
    gemm_p    <<<288, blk, 0, stream>>>(A_frag, LT_frag, P_frag, nrm);
    gemm_cross<<<252, blk, 0, stream>>>(P_frag, nrm, bdot, lmbda, scale, out);
}

// Round 8
// 89.652 us; speedup vs baseline: 1.4037x; 1.0659x over previous
//
#include <hip/hip_runtime.h>

#define D_DIM 1024
#define B_DIM 128
#define C_DIM 1000
#define M_ALL 1152   // 128 x-rows + 1000 mu-rows + 24 zero-pad rows
#define EPSF 1e-6f

typedef __attribute__((ext_vector_type(8))) short short8;   // 8 bf16 = 16B
typedef __attribute__((ext_vector_type(4))) float f32x4;

static __device__ __forceinline__ unsigned short f2bf(float f) {
    union { float f; unsigned int u; } v; v.f = f;
    unsigned int u = v.u;
    u += 0x7fffu + ((u >> 16) & 1u);   // round-to-nearest-even
    return (unsigned short)(u >> 16);
}

// Fragment layout (R4/R5-proven): panel(tile16, kc) = 1KB. Element (row, k):
// kc = k>>5, l = ((k&31)>>3)*16 + (row&15), j = k&7;
// offset_shorts = (tile*32 + kc)*512 + l*8 + j.

// ---------------------------------------------------------------------------
// D1 (unchanged from R7): blocks [0,144): pack 8 A-rows -> fragment bf16 +
// per-row (eps*||a||^2, beta.a). Blocks [144,400): one 64x64 tril(L)^T tile.
// ---------------------------------------------------------------------------
__global__ __launch_bounds__(256)
void pack_all(const float* __restrict__ x, const float* __restrict__ mu,
              const float* __restrict__ beta, const float* __restrict__ L,
              unsigned short* __restrict__ A_frag, unsigned short* __restrict__ LT_frag,
              float* __restrict__ nrm, float* __restrict__ bdot) {
    __shared__ __align__(16) unsigned short s_tile[64 * 72];
    const int tid = threadIdx.x, bid = blockIdx.x;

    if (bid < 144) {
        const int m = bid * 8 + (tid >> 5);         // 8 rows per block
        const int cg = tid & 31;                    // 32 lanes per row
        const float* arow = (m < B_DIM) ? (x + (size_t)m * D_DIM)
                          : (m < B_DIM + C_DIM) ? (mu + (size_t)(m - B_DIM) * D_DIM)
                          : (const float*)0;
        const int mtile = m >> 4, rl = m & 15;
        const int qk = (cg & 7) >> 1, jj = (cg & 1) * 4;
        float sa = 0.f, sb = 0.f;
#pragma unroll
        for (int pass = 0; pass < 8; ++pass) {
            int k = cg * 4 + pass * 128;
            float4 v = arow ? *(const float4*)(arow + k)
                            : make_float4(0.f, 0.f, 0.f, 0.f);
            ushort4 o;
            o.x = f2bf(v.x); o.y = f2bf(v.y); o.z = f2bf(v.z); o.w = f2bf(v.w);
            int kc = (cg >> 3) + pass * 4;
            *(ushort4*)(A_frag + ((size_t)(mtile * 32 + kc)) * 512 + (qk * 16 + rl) * 8 + jj) = o;
            float4 bb = *(const float4*)(beta + k);
            sa += v.x * v.x + v.y * v.y + v.z * v.z + v.w * v.w;
            sb += bb.x * v.x + bb.y * v.y + bb.z * v.z + bb.w * v.w;
        }
#pragma unroll
        for (int off = 16; off > 0; off >>= 1) {
            sa += __shfl_down(sa, off);
            sb += __shfl_down(sb, off);
        }
        if (cg == 0) { nrm[m] = EPSF * sa; bdot[m] = sb; }   // base; gemm_p adds ||P||^2
    } else {
        const int t = bid - 144;                   // 0..255
        const int k0 = (t >> 4) * 64, n0 = (t & 15) * 64;
        const int tn = tid & 63, tq = tid >> 6;    // tq in 0..3
#pragma unroll
        for (int i = 0; i < 16; ++i) {
            int kk = tq + i * 4;
            int k = k0 + kk, n = n0 + tn;
            float v = (k >= n) ? L[(size_t)k * D_DIM + n] : 0.f;   // coalesced in n
            s_tile[tn * 72 + kk] = f2bf(v);                        // [n][k]
        }
        __syncthreads();
        const int p = tid >> 5, s = tid & 31;      // 8 panels x 32 threads
        const int np = p >> 1, kc2 = p & 1;
        const int ntile = (n0 >> 4) + np, kcg = (k0 >> 5) + kc2;
#pragma unroll
        for (int e = 0; e < 2; ++e) {
            int l = s * 2 + e;
            int lq = l >> 4, nr = l & 15;
            short8 vv = *(const short8*)&s_tile[(np * 16 + nr) * 72 + kc2 * 32 + lq * 8];
            *(short8*)(LT_frag + ((size_t)(ntile * 32 + kcg)) * 512 + l * 8) = vv;
        }
    }
}

// ---------------------------------------------------------------------------
// D2: P = A @ tril(L), split-K x2. 1152 tiles x 2 K-halves = 2304 wave-jobs
// = 576 blocks (2 tiles/block). Each wave: <=16 kc iters (unroll 8).
// Halves combine via padded LDS; kh==0 wave runs the epilogue
// (||P_row||^2 atomics + C->fragment reshuffle, R5-proven).
// ---------------------------------------------------------------------------
__global__ __launch_bounds__(256)
void gemm_p(const unsigned short* __restrict__ A_frag,
            const unsigned short* __restrict__ LT_frag,
            unsigned short* __restrict__ P_frag, float* __restrict__ nrm) {
    __shared__ __align__(16) float s_red[2][64][17];             // 8704 B, pad->no conflicts
    __shared__ __align__(16) unsigned short s_resh[2][1024];     // 4096 B
    const int wv = threadIdx.x >> 6, lane = threadIdx.x & 63;
    const int tl = wv >> 1, kh = wv & 1;
    const int tile = blockIdx.x * 2 + tl;          // 0..1151
    const int lrow = lane & 15, q = lane >> 4;
    const int mt = tile >> 5, nt = tile & 31;
    const int kmid = nt + ((32 - nt + 1) >> 1);    // balanced split of [nt,32)
    const int kbeg = kh ? kmid : nt;
    const int kend = kh ? 32 : kmid;

    const unsigned short* Ab0 = A_frag  + ((size_t)(2 * mt) * 32) * 512 + lane * 8;
    const unsigned short* Ab1 = Ab0 + 32 * 512;
    const unsigned short* Bb0 = LT_frag + ((size_t)(2 * nt) * 32) * 512 + lane * 8;
    const unsigned short* Bb1 = Bb0 + 32 * 512;

    f32x4 acc[2][2] = {};
#pragma unroll 8
    for (int kc = kbeg; kc < kend; ++kc) {
        short8 a0 = *(const short8*)(Ab0 + kc * 512);
        short8 a1 = *(const short8*)(Ab1 + kc * 512);
        short8 b0 = *(const short8*)(Bb0 + kc * 512);
        short8 b1 = *(const short8*)(Bb1 + kc * 512);
        acc[0][0] = __builtin_amdgcn_mfma_f32_16x16x32_bf16(a0, b0, acc[0][0], 0, 0, 0);
        acc[0][1] = __builtin_amdgcn_mfma_f32_16x16x32_bf16(a0, b1, acc[0][1], 0, 0, 0);
        acc[1][0] = __builtin_amdgcn_mfma_f32_16x16x32_bf16(a1, b0, acc[1][0], 0, 0, 0);
        acc[1][1] = __builtin_amdgcn_mfma_f32_16x16x32_bf16(a1, b1, acc[1][1], 0, 0, 0);
    }

    if (kh == 1) {
#pragma unroll
        for (int mi = 0; mi < 2; ++mi)
#pragma unroll
        for (int ni = 0; ni < 2; ++ni)
#pragma unroll
        for (int r = 0; r < 4; ++r)
            s_red[tl][lane][(mi * 2 + ni) * 4 + r] = acc[mi][ni][r];
    }
    __syncthreads();
    if (kh == 1) return;
#pragma unroll
    for (int mi = 0; mi < 2; ++mi)
#pragma unroll
    for (int ni = 0; ni < 2; ++ni)
#pragma unroll
    for (int r = 0; r < 4; ++r)
        acc[mi][ni][r] += s_red[tl][lane][(mi * 2 + ni) * 4 + r];

    // ||P_row||^2 partials (C layout: col = lrow + ni*16, row = q*4 + r)
#pragma unroll
    for (int mi = 0; mi < 2; ++mi)
#pragma unroll
    for (int r = 0; r < 4; ++r) {
        float s = acc[mi][0][r] * acc[mi][0][r] + acc[mi][1][r] * acc[mi][1][r];
#pragma unroll
        for (int off = 1; off < 16; off <<= 1) s += __shfl_xor(s, off);
        if (lrow == 0) atomicAdd(&nrm[mt * 32 + mi * 16 + q * 4 + r], s);
    }
    // Reshuffle C-layout -> fragment layout through per-tile LDS
    unsigned short* wls = s_resh[tl];
#pragma unroll
    for (int mi = 0; mi < 2; ++mi)
#pragma unroll
    for (int ni = 0; ni < 2; ++ni) {
        int lp = (ni * 2 + (lrow >> 3)) * 16 + q * 4;
#pragma unroll
        for (int r = 0; r < 4; ++r)
            wls[mi * 512 + (lp + r) * 8 + (lrow & 7)] = f2bf(acc[mi][ni][r]);
    }
    asm volatile("s_waitcnt lgkmcnt(0)" ::: "memory");   // per-wave LDS, no barrier
#pragma unroll
    for (int mi = 0; mi < 2; ++mi) {
        short8 vv = *(const short8*)(wls + mi * 512 + lane * 8);
        *(short8*)(P_frag + ((size_t)((2 * mt + mi) * 32 + nt)) * 512 + lane * 8) = vv;
    }
}

// ---------------------------------------------------------------------------
// D3 (unchanged from R7): cross-GEMM + fused epilogue, split-K x2.
// 504 tiles x 2 K-halves = 1008 wave-jobs = 252 blocks.
// ---------------------------------------------------------------------------
__global__ __launch_bounds__(256)
void gemm_cross(const unsigned short* __restrict__ P_frag,
                const float* __restrict__ nrm, const float* __restrict__ bdot,
                const float* __restrict__ lmbda_p, const float* __restrict__ scale_p,
                float* __restrict__ out) {
    __shared__ f32x4 red[2][64];
    const int wv = threadIdx.x >> 6, lane = threadIdx.x & 63;
    const int tile = blockIdx.x * 2 + (wv >> 1);   // 0..503
    const int kh = wv & 1;
    const int lrow = lane & 15, q = lane >> 4;
    const int bt = tile / 63, ct = tile % 63;
    const unsigned short* up = P_frag + ((size_t)(bt * 32 + kh * 16)) * 512 + lane * 8;
    const unsigned short* vp = P_frag + ((size_t)((8 + ct) * 32 + kh * 16)) * 512 + lane * 8;

    f32x4 acc = {};
#pragma unroll 8
    for (int kc = 0; kc < 16; ++kc) {
        short8 a = *(const short8*)(up + kc * 512);
        short8 b = *(const short8*)(vp + kc * 512);
        acc = __builtin_amdgcn_mfma_f32_16x16x32_bf16(a, b, acc, 0, 0, 0);
    }
    if (kh == 1) red[wv >> 1][lane] = acc;
    __syncthreads();
    if (kh == 1) return;
    f32x4 o = red[wv >> 1][lane];
    acc[0] += o[0]; acc[1] += o[1]; acc[2] += o[2]; acc[3] += o[3];

    const float lm = *lmbda_p, sc = *scale_p;
    const int c = ct * 16 + lrow;
    if (c < C_DIM) {
        float nm = nrm[B_DIM + c], bm = bdot[B_DIM + c];
#pragma unroll
        for (int r = 0; r < 4; ++r) {
            int b = bt * 16 + q * 4 + r;
            float quad = nrm[b] + nm - 2.f * acc[r] + EPSF;
            quad = fmaxf(quad, 0.f);
            float bd = bdot[b] - bm;
            out[b * C_DIM + c] = -sc * (sqrtf(quad) + lm * sqrtf(fmaf(bd, bd, EPSF)));
        }
    }
}

extern "C" void kernel_launch(void* const* d_in, const int* in_sizes, int n_in,
                              void* d_out, int out_size, void* d_ws, size_t ws_size,
                              hipStream_t stream) {
    const float* x     = (const float*)d_in[0];   // [128,1024]
    const float* mu    = (const float*)d_in[1];   // [1000,1024]
    const float* beta  = (const float*)d_in[2];   // [1024]
    const float* L     = (const float*)d_in[3];   // [1024,1024]
    const float* lmbda = (const float*)d_in[4];
    const float* scale = (const float*)d_in[5];
    float* out = (float*)d_out;                   // [128,1000]

    char* ws = (char*)d_ws;
    unsigned short* A_frag  = (unsigned short*)ws;                       // 2359296 B
    unsigned short* LT_frag = (unsigned short*)(ws + 2359296);           // 2097152 B
    unsigned short* P_frag  = (unsigned short*)(ws + 2359296 + 2097152); // 2359296 B
    float* fws  = (float*)(ws + 2359296 + 2097152 + 2359296);
    float* nrm  = fws;             // [1152]
    float* bdot = fws + M_ALL;     // [1152]

    dim3 blk(256);
    pack_all  <<<400, blk, 0, stream>>>(x, mu, beta, L, A_frag, LT_frag, nrm, bdot);
    gemm_p    <<<576, blk, 0, stream>>>(A_frag, LT_frag, P_frag, nrm);
    gemm_cross<<<252, blk, 0, stream>>>(P_frag, nrm, bdot, lmbda, scale, out);
}